// Round 1
// baseline (382.471 us; speedup 1.0000x reference)
//
#include <hip/hip_runtime.h>
#include <hip/hip_bf16.h>

#define N_FEAT 8192
#define D_MODEL 256
#define HEADS 4
#define CELLS 32
#define BATCH 4096
#define HC 128          // HEADS*CELLS
#define NT 32           // n-rows per reps block
#define DC 64           // d-chunk
#define KSPLIT 8
#define KCH (N_FEAT / KSPLIT)   // 1024

typedef __attribute__((ext_vector_type(8))) short bf16x8;
typedef __attribute__((ext_vector_type(4))) float f32x4;

__device__ __forceinline__ unsigned short f32_to_bf16(float f) {
    union { float f; unsigned u; } v; v.f = f;
    unsigned r = v.u + 0x7fffu + ((v.u >> 16) & 1u);
    return (unsigned short)(r >> 16);
}

__device__ __forceinline__ float bf16_to_f32(unsigned short h) {
    union { unsigned u; float f; } v; v.u = ((unsigned)h) << 16;
    return v.f;
}

// ---------------------------------------------------------------------------
// Stage 1 (fused): tropical scores (tiled max-plus GEMM) -> top-2 -> sigmoid
// blend -> write reps (bf16) AND repsT (bf16), one block per 32 feature rows.
// ---------------------------------------------------------------------------
__global__ __launch_bounds__(256) void reps_kernel(
    const float* __restrict__ proj, const float* __restrict__ rw,
    const float* __restrict__ rb, const float* __restrict__ cb,
    unsigned short* __restrict__ reps_bf, unsigned short* __restrict__ repsT)
{
    __shared__ float latS[NT][DC + 4];
    __shared__ float wS[HC][DC + 4];
    __shared__ float sc[NT][HC + 4];
    __shared__ float T[NT][257];
    __shared__ float gateS[NT][HEADS];
    __shared__ int   widxS[NT][HEADS], ridxS[NT][HEADS];

    const int t = threadIdx.x;
    const int nbase = blockIdx.x * NT;
    const int tx = t & 31, ty = t >> 5;
    const int hc0 = tx * 4, n0 = ty * 4;

    float acc[4][4];
    #pragma unroll
    for (int i = 0; i < 4; ++i)
        #pragma unroll
        for (int j = 0; j < 4; ++j)
            acc[i][j] = -3.4e38f;

    for (int dk = 0; dk < D_MODEL; dk += DC) {
        __syncthreads();
        {
            int f = t;
            #pragma unroll
            for (int i = 0; i < 2; ++i, f += 256) {
                const int row = f >> 4, c4 = f & 15;
                float4 v = *(const float4*)&proj[(long)(nbase + row) * D_MODEL + dk + c4 * 4];
                *(float4*)&latS[row][c4 * 4] = v;
            }
        }
        {
            int f = t;
            #pragma unroll
            for (int i = 0; i < 8; ++i, f += 256) {
                const int row = f >> 4, c4 = f & 15;
                float4 v = *(const float4*)&rw[(long)row * D_MODEL + dk + c4 * 4];
                *(float4*)&wS[row][c4 * 4] = v;
            }
        }
        __syncthreads();

        #pragma unroll 4
        for (int d = 0; d < DC; d += 4) {
            float4 la[4], wv[4];
            #pragma unroll
            for (int i = 0; i < 4; ++i) la[i] = *(const float4*)&latS[n0 + i][d];
            #pragma unroll
            for (int j = 0; j < 4; ++j) wv[j] = *(const float4*)&wS[hc0 + j][d];
            #pragma unroll
            for (int i = 0; i < 4; ++i)
                #pragma unroll
                for (int j = 0; j < 4; ++j) {
                    float m01 = fmaxf(la[i].x + wv[j].x, la[i].y + wv[j].y);
                    float m23 = fmaxf(la[i].z + wv[j].z, la[i].w + wv[j].w);
                    acc[i][j] = fmaxf(acc[i][j], fmaxf(m01, m23));
                }
        }
    }

    #pragma unroll
    for (int j = 0; j < 4; ++j) {
        const float rbv = rb[hc0 + j];
        #pragma unroll
        for (int i = 0; i < 4; ++i)
            sc[n0 + i][hc0 + j] = acc[i][j] + rbv;
    }
    __syncthreads();

    if (t < NT * HEADS) {
        const int n = t >> 2, h = t & 3;
        float v1 = -3.4e38f, v2 = -3.4e38f; int i1 = 0, i2 = 0;
        #pragma unroll
        for (int c = 0; c < CELLS; ++c) {
            float s = sc[n][h * CELLS + c];
            if (s > v1) { v2 = v1; i2 = i1; v1 = s; i1 = c; }
            else if (s > v2) { v2 = s; i2 = c; }
        }
        gateS[n][h] = 1.0f / (1.0f + __expf(-(v1 - v2)));
        widxS[n][h] = i1; ridxS[n][h] = i2;
    }
    __syncthreads();

    #pragma unroll 4
    for (int r = 0; r < NT; ++r) {
        float val = proj[(long)(nbase + r) * D_MODEL + t];
        #pragma unroll
        for (int h = 0; h < HEADS; ++h) {
            const float g = gateS[r][h];
            const float wv = cb[(long)(h * CELLS + widxS[r][h]) * D_MODEL + t];
            const float rv = cb[(long)(h * CELLS + ridxS[r][h]) * D_MODEL + t];
            val += g * wv + (1.0f - g) * rv;   // CODE_SCALE = 1
        }
        reps_bf[(long)(nbase + r) * D_MODEL + t] = f32_to_bf16(val);
        T[r][t] = val;
    }
    __syncthreads();

    #pragma unroll
    for (int i = 0; i < 32; ++i) {
        const int d = i * 8 + (t >> 5);
        const int n = t & 31;
        repsT[(long)d * N_FEAT + nbase + n] = f32_to_bf16(T[n][d]);
    }
}

// ---------------------------------------------------------------------------
// Stage 2: hidden_part[ks] = x[:, ks-chunk] @ reps[ks-chunk, :]  (bf16 out)
// LDS-FREE: each lane loads its MFMA fragments directly from global
// (fragments are row-contiguous 32B/16B runs in x and repsT; L1/L2/LLC
// dedup the 2x wave duplication). Zero barriers, zero bank conflicts.
// 64x128 tile, 4 waves (2x2), acc[2][4], K-split x8, depth-1 reg prefetch.
// ---------------------------------------------------------------------------
__global__ __launch_bounds__(256, 4) void gemm1_kernel(
    const float* __restrict__ x, const unsigned short* __restrict__ repsT,
    unsigned short* __restrict__ hidden_part)
{
    const int m0 = blockIdx.y * 64;
    const int n0 = blockIdx.x * 128;
    const int ks = blockIdx.z;
    const int t = threadIdx.x;
    const int wave = t >> 6, lane = t & 63;
    const int wm = (wave >> 1) * 32, wn = (wave & 1) * 64;
    const int quad = lane >> 4, l16 = lane & 15;
    const int kbeg = ks * KCH;

    // per-lane fragment source pointers (row-contiguous runs)
    const float* xa0 = x + (long)(m0 + wm + l16) * N_FEAT + kbeg + quad * 8;
    const float* xa1 = xa0 + 16 * N_FEAT;
    const unsigned short* bb0 = repsT + (long)(n0 + wn + l16) * N_FEAT + kbeg + quad * 8;

    f32x4 acc[2][4];
    #pragma unroll
    for (int i = 0; i < 2; ++i)
        #pragma unroll
        for (int j = 0; j < 4; ++j)
            acc[i][j] = (f32x4){0.f, 0.f, 0.f, 0.f};

    // prefetch iter 0
    float4 pa[2][2];
    uint4 pb[4];
    pa[0][0] = ((const float4*)xa0)[0]; pa[0][1] = ((const float4*)xa0)[1];
    pa[1][0] = ((const float4*)xa1)[0]; pa[1][1] = ((const float4*)xa1)[1];
    #pragma unroll
    for (int j = 0; j < 4; ++j)
        pb[j] = *(const uint4*)(bb0 + j * 16 * N_FEAT);

    #pragma unroll 1
    for (int k0 = 0; k0 < KCH; k0 += 32) {
        // consume prefetched regs into locals so next loads can issue early
        float4 ca0 = pa[0][0], ca1 = pa[0][1], ca2 = pa[1][0], ca3 = pa[1][1];
        uint4 cb[4] = {pb[0], pb[1], pb[2], pb[3]};

        if (k0 + 32 < KCH) {
            const float* a0 = xa0 + k0 + 32;
            const float* a1 = xa1 + k0 + 32;
            pa[0][0] = ((const float4*)a0)[0]; pa[0][1] = ((const float4*)a0)[1];
            pa[1][0] = ((const float4*)a1)[0]; pa[1][1] = ((const float4*)a1)[1];
            #pragma unroll
            for (int j = 0; j < 4; ++j)
                pb[j] = *(const uint4*)(bb0 + j * 16 * N_FEAT + k0 + 32);
        }

        // convert A fragments f32 -> bf16 in-register
        bf16x8 af[2];
        {
            union { unsigned short u[8]; bf16x8 v; } c0, c1;
            float f0[8] = {ca0.x, ca0.y, ca0.z, ca0.w, ca1.x, ca1.y, ca1.z, ca1.w};
            float f1[8] = {ca2.x, ca2.y, ca2.z, ca2.w, ca3.x, ca3.y, ca3.z, ca3.w};
            #pragma unroll
            for (int e = 0; e < 8; ++e) { c0.u[e] = f32_to_bf16(f0[e]); c1.u[e] = f32_to_bf16(f1[e]); }
            af[0] = c0.v; af[1] = c1.v;
        }

        #pragma unroll
        for (int i = 0; i < 2; ++i)
            #pragma unroll
            for (int j = 0; j < 4; ++j)
                acc[i][j] = __builtin_amdgcn_mfma_f32_16x16x32_bf16(
                    af[i], *(const bf16x8*)&cb[j], acc[i][j], 0, 0, 0);
    }

    unsigned short* hp = hidden_part + (long)ks * BATCH * D_MODEL;
    #pragma unroll
    for (int i = 0; i < 2; ++i)
        #pragma unroll
        for (int j = 0; j < 4; ++j) {
            const int col = n0 + wn + j * 16 + l16;
            #pragma unroll
            for (int r = 0; r < 4; ++r) {
                const int rowg = m0 + wm + i * 16 + quad * 4 + r;
                hp[(long)rowg * D_MODEL + col] = f32_to_bf16(acc[i][j][r]);
            }
        }
}

// ---------------------------------------------------------------------------
// Stage 2b: hidden_bf16 = bf16( sum of KSPLIT bf16 K-split partials )
// ---------------------------------------------------------------------------
__global__ __launch_bounds__(256) void reduce_kernel(
    const unsigned short* __restrict__ hp, unsigned short* __restrict__ hb)
{
    const int id = blockIdx.x * 256 + threadIdx.x;   // over 131072 uint4 (8 bf16)
    const int S = BATCH * D_MODEL / 8;
    const uint4* p = (const uint4*)hp;
    float s[8] = {0.f, 0.f, 0.f, 0.f, 0.f, 0.f, 0.f, 0.f};
    #pragma unroll
    for (int k = 0; k < KSPLIT; ++k) {
        uint4 v = p[(long)k * S + id];
        unsigned short e[8];
        *(uint4*)e = v;
        #pragma unroll
        for (int j = 0; j < 8; ++j) s[j] += bf16_to_f32(e[j]);
    }
    unsigned short o[8];
    #pragma unroll
    for (int j = 0; j < 8; ++j) o[j] = f32_to_bf16(s[j]);
    ((uint4*)hb)[id] = *(const uint4*)o;
}

// ---------------------------------------------------------------------------
// Stage 3: out = relu(hidden @ reps^T + bias)   M=4096 N=8192 K=256
// B^T is reps itself (row n, contiguous d); reg-prefetch pipeline
// ---------------------------------------------------------------------------
__global__ __launch_bounds__(256, 4) void gemm2_kernel(
    const unsigned short* __restrict__ hb, const unsigned short* __restrict__ reps,
    const float* __restrict__ bias, float* __restrict__ out)
{
    __shared__ unsigned short As[128 * 32];
    __shared__ unsigned short Bs[128 * 32];

    const int m0 = blockIdx.y * 128;   // batch
    const int n0 = blockIdx.x * 128;   // features
    const int t = threadIdx.x;
    const int wave = t >> 6, lane = t & 63;
    const int wm = (wave >> 1) * 64, wn = (wave & 1) * 64;
    const int quad = lane >> 4, l16 = lane & 15;

    f32x4 acc[4][4];
    #pragma unroll
    for (int i = 0; i < 4; ++i)
        #pragma unroll
        for (int j = 0; j < 4; ++j)
            acc[i][j] = (f32x4){0.f, 0.f, 0.f, 0.f};

    const int row = t >> 1, hf = t & 1;
    const unsigned short* asrc = hb + (long)(m0 + row) * D_MODEL + hf * 16;
    const unsigned short* bsrc = reps + (long)(n0 + row) * D_MODEL + hf * 16;
    unsigned short* aw = &As[row * 32 + hf * 16];
    unsigned short* bw = &Bs[row * 32 + hf * 16];

    uint4 pa0, pa1, pb0, pb1;
    {
        const uint4* as = (const uint4*)(asrc);
        pa0 = as[0]; pa1 = as[1];
        const uint4* bs = (const uint4*)(bsrc);
        pb0 = bs[0]; pb1 = bs[1];
    }

    for (int k0 = 0; k0 < D_MODEL; k0 += 32) {
        uint4 a0 = pa0, a1 = pa1, b0 = pb0, b1 = pb1;
        __syncthreads();
        *((uint4*)aw)       = a0;
        *((uint4*)(aw + 8)) = a1;
        *((uint4*)bw)       = b0;
        *((uint4*)(bw + 8)) = b1;
        __syncthreads();

        if (k0 + 32 < D_MODEL) {
            const uint4* as = (const uint4*)(asrc + k0 + 32);
            pa0 = as[0]; pa1 = as[1];
            const uint4* bs = (const uint4*)(bsrc + k0 + 32);
            pb0 = bs[0]; pb1 = bs[1];
        }

        bf16x8 af[4], bfr[4];
        #pragma unroll
        for (int i = 0; i < 4; ++i)
            af[i] = *((const bf16x8*)&As[(wm + i * 16 + l16) * 32 + quad * 8]);
        #pragma unroll
        for (int j = 0; j < 4; ++j)
            bfr[j] = *((const bf16x8*)&Bs[(wn + j * 16 + l16) * 32 + quad * 8]);
        #pragma unroll
        for (int i = 0; i < 4; ++i)
            #pragma unroll
            for (int j = 0; j < 4; ++j)
                acc[i][j] = __builtin_amdgcn_mfma_f32_16x16x32_bf16(
                    af[i], bfr[j], acc[i][j], 0, 0, 0);
    }

    #pragma unroll
    for (int i = 0; i < 4; ++i)
        #pragma unroll
        for (int j = 0; j < 4; ++j) {
            const int col = n0 + wn + j * 16 + l16;
            const float bv = bias[col];
            #pragma unroll
            for (int r = 0; r < 4; ++r) {
                const int rowg = m0 + wm + i * 16 + quad * 4 + r;
                out[(long)rowg * N_FEAT + col] = fmaxf(acc[i][j][r] + bv, 0.f);
            }
        }
}

// ---------------------------------------------------------------------------
extern "C" void kernel_launch(void* const* d_in, const int* in_sizes, int n_in,
                              void* d_out, int out_size, void* d_ws, size_t ws_size,
                              hipStream_t stream) {
    const float* x    = (const float*)d_in[0];
    const float* proj = (const float*)d_in[1];
    const float* rw   = (const float*)d_in[2];
    const float* rb   = (const float*)d_in[3];
    const float* cb   = (const float*)d_in[4];
    const float* bias = (const float*)d_in[5];
    float* out = (float*)d_out;

    char* ws = (char*)d_ws;
    unsigned short* reps_bf = (unsigned short*)ws;                 // 4 MB
    unsigned short* repsT   = (unsigned short*)(ws + (4u << 20));  // 4 MB
    unsigned short* hid_prt = (unsigned short*)(ws + (8u << 20));  // 16 MB (8 x 2 MB)
    unsigned short* hid_bf  = (unsigned short*)(ws + (24u << 20)); // 2 MB

    reps_kernel<<<N_FEAT / NT, 256, 0, stream>>>(proj, rw, rb, cb, reps_bf, repsT);
    gemm1_kernel<<<dim3(2, 64, KSPLIT), 256, 0, stream>>>(x, repsT, hid_prt);
    reduce_kernel<<<512, 256, 0, stream>>>(hid_prt, hid_bf);
    gemm2_kernel<<<dim3(64, 32), 256, 0, stream>>>(hid_bf, reps_bf, bias, out);
}

// Round 2
// 326.804 us; speedup vs baseline: 1.1703x; 1.1703x over previous
//
#include <hip/hip_runtime.h>
#include <hip/hip_bf16.h>

#define N_FEAT 8192
#define D_MODEL 256
#define HEADS 4
#define CELLS 32
#define BATCH 4096
#define HC 128          // HEADS*CELLS
#define NT 32           // n-rows per reps block
#define DC 64           // d-chunk
#define KSPLIT 16
#define KCH (N_FEAT / KSPLIT)   // 512

typedef __attribute__((ext_vector_type(8))) short bf16x8;
typedef __attribute__((ext_vector_type(4))) float f32x4;

__device__ __forceinline__ unsigned short f32_to_bf16(float f) {
    union { float f; unsigned u; } v; v.f = f;
    unsigned r = v.u + 0x7fffu + ((v.u >> 16) & 1u);
    return (unsigned short)(r >> 16);
}

__device__ __forceinline__ float bf16_to_f32(unsigned short h) {
    union { unsigned u; float f; } v; v.u = ((unsigned)h) << 16;
    return v.f;
}

// direct global->LDS DMA, 16B per lane; LDS dest must be wave-uniform base
__device__ __forceinline__ void gload16(const void* gsrc, void* ldst) {
    __builtin_amdgcn_global_load_lds(
        (const __attribute__((address_space(1))) unsigned int*)gsrc,
        (__attribute__((address_space(3))) unsigned int*)ldst, 16, 0, 0);
}

// ---------------------------------------------------------------------------
// Stage 1 (fused): tropical scores (tiled max-plus GEMM) -> top-2 -> sigmoid
// blend -> write reps (bf16) AND repsT (bf16), one block per 32 feature rows.
// ---------------------------------------------------------------------------
__global__ __launch_bounds__(256) void reps_kernel(
    const float* __restrict__ proj, const float* __restrict__ rw,
    const float* __restrict__ rb, const float* __restrict__ cb,
    unsigned short* __restrict__ reps_bf, unsigned short* __restrict__ repsT)
{
    __shared__ float latS[NT][DC + 4];
    __shared__ float wS[HC][DC + 4];
    __shared__ float sc[NT][HC + 4];
    __shared__ float T[NT][257];
    __shared__ float gateS[NT][HEADS];
    __shared__ int   widxS[NT][HEADS], ridxS[NT][HEADS];

    const int t = threadIdx.x;
    const int nbase = blockIdx.x * NT;
    const int tx = t & 31, ty = t >> 5;
    const int hc0 = tx * 4, n0 = ty * 4;

    float acc[4][4];
    #pragma unroll
    for (int i = 0; i < 4; ++i)
        #pragma unroll
        for (int j = 0; j < 4; ++j)
            acc[i][j] = -3.4e38f;

    for (int dk = 0; dk < D_MODEL; dk += DC) {
        __syncthreads();
        {
            int f = t;
            #pragma unroll
            for (int i = 0; i < 2; ++i, f += 256) {
                const int row = f >> 4, c4 = f & 15;
                float4 v = *(const float4*)&proj[(long)(nbase + row) * D_MODEL + dk + c4 * 4];
                *(float4*)&latS[row][c4 * 4] = v;
            }
        }
        {
            int f = t;
            #pragma unroll
            for (int i = 0; i < 8; ++i, f += 256) {
                const int row = f >> 4, c4 = f & 15;
                float4 v = *(const float4*)&rw[(long)row * D_MODEL + dk + c4 * 4];
                *(float4*)&wS[row][c4 * 4] = v;
            }
        }
        __syncthreads();

        #pragma unroll 4
        for (int d = 0; d < DC; d += 4) {
            float4 la[4], wv[4];
            #pragma unroll
            for (int i = 0; i < 4; ++i) la[i] = *(const float4*)&latS[n0 + i][d];
            #pragma unroll
            for (int j = 0; j < 4; ++j) wv[j] = *(const float4*)&wS[hc0 + j][d];
            #pragma unroll
            for (int i = 0; i < 4; ++i)
                #pragma unroll
                for (int j = 0; j < 4; ++j) {
                    float m01 = fmaxf(la[i].x + wv[j].x, la[i].y + wv[j].y);
                    float m23 = fmaxf(la[i].z + wv[j].z, la[i].w + wv[j].w);
                    acc[i][j] = fmaxf(acc[i][j], fmaxf(m01, m23));
                }
        }
    }

    #pragma unroll
    for (int j = 0; j < 4; ++j) {
        const float rbv = rb[hc0 + j];
        #pragma unroll
        for (int i = 0; i < 4; ++i)
            sc[n0 + i][hc0 + j] = acc[i][j] + rbv;
    }
    __syncthreads();

    if (t < NT * HEADS) {
        const int n = t >> 2, h = t & 3;
        float v1 = -3.4e38f, v2 = -3.4e38f; int i1 = 0, i2 = 0;
        #pragma unroll
        for (int c = 0; c < CELLS; ++c) {
            float s = sc[n][h * CELLS + c];
            if (s > v1) { v2 = v1; i2 = i1; v1 = s; i1 = c; }
            else if (s > v2) { v2 = s; i2 = c; }
        }
        gateS[n][h] = 1.0f / (1.0f + __expf(-(v1 - v2)));
        widxS[n][h] = i1; ridxS[n][h] = i2;
    }
    __syncthreads();

    #pragma unroll 4
    for (int r = 0; r < NT; ++r) {
        float val = proj[(long)(nbase + r) * D_MODEL + t];
        #pragma unroll
        for (int h = 0; h < HEADS; ++h) {
            const float g = gateS[r][h];
            const float wv = cb[(long)(h * CELLS + widxS[r][h]) * D_MODEL + t];
            const float rv = cb[(long)(h * CELLS + ridxS[r][h]) * D_MODEL + t];
            val += g * wv + (1.0f - g) * rv;   // CODE_SCALE = 1
        }
        reps_bf[(long)(nbase + r) * D_MODEL + t] = f32_to_bf16(val);
        T[r][t] = val;
    }
    __syncthreads();

    #pragma unroll
    for (int i = 0; i < 32; ++i) {
        const int d = i * 8 + (t >> 5);
        const int n = t & 31;
        repsT[(long)d * N_FEAT + nbase + n] = f32_to_bf16(T[n][d]);
    }
}

// ---------------------------------------------------------------------------
// Stage 2: hidden_part[ks] = x[:, ks-chunk] @ reps[ks-chunk, :]  (bf16 out)
// 128x128 tile, 4 waves, 4x4 16x16x32 bf16 MFMA, K-split x16.
// T3-minimum 2-phase: global_load_lds (width 16) into double-buffered LDS,
// stage-next issued BEFORE compute, ONE barrier per K-step. A staged as f32
// (DMA can't convert), f32->bf16 during fragment read (VALU pipe, overlaps
// MFMA). No LDS swizzle: T2 measured-null on 2-phase 128^2 structures.
// ---------------------------------------------------------------------------
__global__ __launch_bounds__(256) void gemm1_kernel(
    const float* __restrict__ x, const unsigned short* __restrict__ repsT,
    unsigned short* __restrict__ hidden_part)
{
    __shared__ float As[2][128 * 32];            // 2 x 16 KB (f32)
    __shared__ unsigned short Bs[2][128 * 32];   // 2 x 8 KB (bf16)

    const int m0 = blockIdx.y * 128;
    const int n0 = blockIdx.x * 128;
    const int ks = blockIdx.z;
    const int t = threadIdx.x;
    const int wave = t >> 6, lane = t & 63;
    const int wm = (wave >> 1) * 64, wn = (wave & 1) * 64;
    const int quad = lane >> 4, l16 = lane & 15;
    const int kbeg = ks * KCH, kend = kbeg + KCH;

    // staging geometry (linear LDS fill: lane offset = lane*16B, HW-added)
    const int arow = (lane >> 3);        // within 8-row chunk (f32: 128B rows)
    const int akf  = (lane & 7) * 4;     // f32 col
    const int brow = (lane >> 2);        // within 16-row chunk (bf16: 64B rows)
    const int bkf  = (lane & 3) * 8;     // bf16 col

    f32x4 acc[4][4];
    #pragma unroll
    for (int i = 0; i < 4; ++i)
        #pragma unroll
        for (int j = 0; j < 4; ++j)
            acc[i][j] = (f32x4){0.f, 0.f, 0.f, 0.f};

    // prologue: stage k-step 0 into buffer 0
    #pragma unroll
    for (int i = 0; i < 4; ++i) {
        const int chunk = wave * 4 + i;                    // 16 x 1KB A chunks
        gload16(&x[(long)(m0 + chunk * 8 + arow) * N_FEAT + kbeg + akf],
                &As[0][chunk * 256]);
    }
    #pragma unroll
    for (int i = 0; i < 2; ++i) {
        const int chunk = wave * 2 + i;                    // 8 x 1KB B chunks
        gload16(&repsT[(long)(n0 + chunk * 16 + brow) * N_FEAT + kbeg + bkf],
                &Bs[0][chunk * 512]);
    }
    __syncthreads();

    int cur = 0;
    #pragma unroll 1
    for (int k0 = kbeg; k0 < kend; k0 += 32) {
        // issue next k-step's DMA into the other buffer (in flight across MFMAs)
        if (k0 + 32 < kend) {
            #pragma unroll
            for (int i = 0; i < 4; ++i) {
                const int chunk = wave * 4 + i;
                gload16(&x[(long)(m0 + chunk * 8 + arow) * N_FEAT + k0 + 32 + akf],
                        &As[cur ^ 1][chunk * 256]);
            }
            #pragma unroll
            for (int i = 0; i < 2; ++i) {
                const int chunk = wave * 2 + i;
                gload16(&repsT[(long)(n0 + chunk * 16 + brow) * N_FEAT + k0 + 32 + bkf],
                        &Bs[cur ^ 1][chunk * 512]);
            }
        }

        // fragments from current buffer
        bf16x8 af[4], bfr[4];
        #pragma unroll
        for (int i = 0; i < 4; ++i) {
            const float4 a0 = *(const float4*)&As[cur][(wm + i * 16 + l16) * 32 + quad * 8];
            const float4 a1 = *(const float4*)&As[cur][(wm + i * 16 + l16) * 32 + quad * 8 + 4];
            union { unsigned short u[8]; bf16x8 v; } c;
            c.u[0] = f32_to_bf16(a0.x); c.u[1] = f32_to_bf16(a0.y);
            c.u[2] = f32_to_bf16(a0.z); c.u[3] = f32_to_bf16(a0.w);
            c.u[4] = f32_to_bf16(a1.x); c.u[5] = f32_to_bf16(a1.y);
            c.u[6] = f32_to_bf16(a1.z); c.u[7] = f32_to_bf16(a1.w);
            af[i] = c.v;
        }
        #pragma unroll
        for (int j = 0; j < 4; ++j)
            bfr[j] = *((const bf16x8*)&Bs[cur][(wn + j * 16 + l16) * 32 + quad * 8]);

        #pragma unroll
        for (int i = 0; i < 4; ++i)
            #pragma unroll
            for (int j = 0; j < 4; ++j)
                acc[i][j] = __builtin_amdgcn_mfma_f32_16x16x32_bf16(
                    af[i], bfr[j], acc[i][j], 0, 0, 0);

        // drain my DMAs + all waves done reading cur, then swap
        __syncthreads();
        cur ^= 1;
    }

    unsigned short* hp = hidden_part + (long)ks * BATCH * D_MODEL;
    #pragma unroll
    for (int i = 0; i < 4; ++i)
        #pragma unroll
        for (int j = 0; j < 4; ++j) {
            const int col = n0 + wn + j * 16 + l16;
            #pragma unroll
            for (int r = 0; r < 4; ++r) {
                const int rowg = m0 + wm + i * 16 + quad * 4 + r;
                hp[(long)rowg * D_MODEL + col] = f32_to_bf16(acc[i][j][r]);
            }
        }
}

// ---------------------------------------------------------------------------
// Stage 2b: hidden_bf16 = bf16( sum of 16 bf16 K-split partials )
// ---------------------------------------------------------------------------
__global__ __launch_bounds__(256) void reduce_kernel(
    const unsigned short* __restrict__ hp, unsigned short* __restrict__ hb)
{
    const int id = blockIdx.x * 256 + threadIdx.x;   // over 131072 uint4 (8 bf16)
    const int S = BATCH * D_MODEL / 8;
    const uint4* p = (const uint4*)hp;
    float s[8] = {0.f, 0.f, 0.f, 0.f, 0.f, 0.f, 0.f, 0.f};
    #pragma unroll
    for (int k = 0; k < KSPLIT; ++k) {
        uint4 v = p[(long)k * S + id];
        unsigned short e[8];
        *(uint4*)e = v;
        #pragma unroll
        for (int j = 0; j < 8; ++j) s[j] += bf16_to_f32(e[j]);
    }
    unsigned short o[8];
    #pragma unroll
    for (int j = 0; j < 8; ++j) o[j] = f32_to_bf16(s[j]);
    ((uint4*)hb)[id] = *(const uint4*)o;
}

// ---------------------------------------------------------------------------
// Stage 3: out = relu(hidden @ reps^T + bias)   M=4096 N=8192 K=256
// Same 2-phase global_load_lds template, both operands bf16 (16 KB x 2 LDS).
// ---------------------------------------------------------------------------
__global__ __launch_bounds__(256) void gemm2_kernel(
    const unsigned short* __restrict__ hb, const unsigned short* __restrict__ reps,
    const float* __restrict__ bias, float* __restrict__ out)
{
    __shared__ unsigned short As[2][128 * 32];   // 2 x 8 KB
    __shared__ unsigned short Bs[2][128 * 32];   // 2 x 8 KB

    const int m0 = blockIdx.y * 128;   // batch
    const int n0 = blockIdx.x * 128;   // features
    const int t = threadIdx.x;
    const int wave = t >> 6, lane = t & 63;
    const int wm = (wave >> 1) * 64, wn = (wave & 1) * 64;
    const int quad = lane >> 4, l16 = lane & 15;

    const int brow = (lane >> 2);        // within 16-row chunk (bf16: 64B rows)
    const int bkf  = (lane & 3) * 8;     // bf16 col

    f32x4 acc[4][4];
    #pragma unroll
    for (int i = 0; i < 4; ++i)
        #pragma unroll
        for (int j = 0; j < 4; ++j)
            acc[i][j] = (f32x4){0.f, 0.f, 0.f, 0.f};

    // prologue: stage k-step 0
    #pragma unroll
    for (int i = 0; i < 2; ++i) {
        const int chunk = wave * 2 + i;                    // 8 x 1KB chunks each
        gload16(&hb[(long)(m0 + chunk * 16 + brow) * D_MODEL + bkf],
                &As[0][chunk * 512]);
        gload16(&reps[(long)(n0 + chunk * 16 + brow) * D_MODEL + bkf],
                &Bs[0][chunk * 512]);
    }
    __syncthreads();

    int cur = 0;
    #pragma unroll 1
    for (int k0 = 0; k0 < D_MODEL; k0 += 32) {
        if (k0 + 32 < D_MODEL) {
            #pragma unroll
            for (int i = 0; i < 2; ++i) {
                const int chunk = wave * 2 + i;
                gload16(&hb[(long)(m0 + chunk * 16 + brow) * D_MODEL + k0 + 32 + bkf],
                        &As[cur ^ 1][chunk * 512]);
                gload16(&reps[(long)(n0 + chunk * 16 + brow) * D_MODEL + k0 + 32 + bkf],
                        &Bs[cur ^ 1][chunk * 512]);
            }
        }

        bf16x8 af[4], bfr[4];
        #pragma unroll
        for (int i = 0; i < 4; ++i)
            af[i] = *((const bf16x8*)&As[cur][(wm + i * 16 + l16) * 32 + quad * 8]);
        #pragma unroll
        for (int j = 0; j < 4; ++j)
            bfr[j] = *((const bf16x8*)&Bs[cur][(wn + j * 16 + l16) * 32 + quad * 8]);
        #pragma unroll
        for (int i = 0; i < 4; ++i)
            #pragma unroll
            for (int j = 0; j < 4; ++j)
                acc[i][j] = __builtin_amdgcn_mfma_f32_16x16x32_bf16(
                    af[i], bfr[j], acc[i][j], 0, 0, 0);

        __syncthreads();
        cur ^= 1;
    }

    #pragma unroll
    for (int i = 0; i < 4; ++i)
        #pragma unroll
        for (int j = 0; j < 4; ++j) {
            const int col = n0 + wn + j * 16 + l16;
            const float bv = bias[col];
            #pragma unroll
            for (int r = 0; r < 4; ++r) {
                const int rowg = m0 + wm + i * 16 + quad * 4 + r;
                out[(long)rowg * N_FEAT + col] = fmaxf(acc[i][j][r] + bv, 0.f);
            }
        }
}

// ---------------------------------------------------------------------------
extern "C" void kernel_launch(void* const* d_in, const int* in_sizes, int n_in,
                              void* d_out, int out_size, void* d_ws, size_t ws_size,
                              hipStream_t stream) {
    const float* x    = (const float*)d_in[0];
    const float* proj = (const float*)d_in[1];
    const float* rw   = (const float*)d_in[2];
    const float* rb   = (const float*)d_in[3];
    const float* cb   = (const float*)d_in[4];
    const float* bias = (const float*)d_in[5];
    float* out = (float*)d_out;

    char* ws = (char*)d_ws;
    unsigned short* reps_bf = (unsigned short*)ws;                 // 4 MB
    unsigned short* repsT   = (unsigned short*)(ws + (4u << 20));  // 4 MB
    unsigned short* hid_prt = (unsigned short*)(ws + (8u << 20));  // 32 MB (16 x 2 MB)
    unsigned short* hid_bf  = (unsigned short*)(ws + (40u << 20)); // 2 MB

    reps_kernel<<<N_FEAT / NT, 256, 0, stream>>>(proj, rw, rb, cb, reps_bf, repsT);
    gemm1_kernel<<<dim3(2, 32, KSPLIT), 256, 0, stream>>>(x, repsT, hid_prt);
    reduce_kernel<<<512, 256, 0, stream>>>(hid_prt, hid_bf);
    gemm2_kernel<<<dim3(64, 32), 256, 0, stream>>>(hid_bf, reps_bf, bias, out);
}